// Round 9
// baseline (40.873 us; speedup 1.0000x reference)
//
#include <hip/hip_runtime.h>
#include <stdint.h>

#define LOG_N   18
#define N_PER   262144              // 2^18 elements per array (H*W)
#define BATCHES 64
#define NBINS   20480               // 2 signs * 80 exponents * 128 mantissa bins
#define HALF    10240
#define HTPB    1024
#define SPLITS  4                   // blocks per segment
#define CHUNK   (N_PER / SPLITS)    // 65536 elements per block
#define GTPB    1024
#define BPT     (NBINS / GTPB)      // 20 bins per integ thread
#define HWORDS  (NBINS / 2)         // packed u16 words per slice

__device__ __forceinline__ uint32_t f2u(float f) {
    uint32_t u = __float_as_uint(f);
    return (u & 0x80000000u) ? ~u : (u | 0x80000000u);
}
// float value of a 16-bit truncated key
__device__ __forceinline__ float key2f(uint32_t k16) {
    uint32_t x = k16 << 16;
    uint32_t u = (x & 0x80000000u) ? (x ^ 0x80000000u) : ~x;
    return __uint_as_float(u);
}
// compress u16 key into [0, NBINS): negatives [0x3800,0x6000) -> [0,HALF),
// positives [0xA000,0xC800) -> [HALF,NBINS). Out-of-range (|x|<2^-63 or
// |x|>2^16) clamps to the nearest edge bin: value error <= 2^-63 width.
__device__ __forceinline__ uint32_t comp16(uint32_t k) {
    if (k >= 0x8000u) {
        uint32_t c = (k < 0xA000u) ? 0u : (k - 0xA000u);
        if (c > HALF - 1u) c = HALF - 1u;
        return HALF + c;
    } else {
        int c = (int)k - 0x3800;
        if (c < 0) c = 0;
        if (c > HALF - 1) c = HALF - 1;
        return (uint32_t)c;
    }
}
__device__ __forceinline__ uint32_t dekey(uint32_t c) {
    return (c < HALF) ? (0x3800u + c) : (0xA000u + (c - HALF));
}
__device__ __forceinline__ void hadd(uint32_t* h, float f) {
    atomicAdd(&h[comp16(f2u(f) >> 16)], 1u);
}

// SPLITS blocks per segment. Unpacked u32 LDS histogram (80 KB, 2 blocks/CU).
// 8 float4 loads issued per iteration (8 KB/wave in flight) to cover HBM
// latency; epilogue stores a packed-u16 slice (no global atomics, no memset).
__global__ __launch_bounds__(HTPB) void hist_kernel(
        const float* t1, const float* t2, int base_seg, uint32_t* slices) {
    __shared__ uint32_t h[NBINS];
    int tid = threadIdx.x;
    {
        uint4 z; z.x = 0; z.y = 0; z.z = 0; z.w = 0;
        uint4* h4 = (uint4*)h;
        for (int i = tid; i < NBINS / 4; i += HTPB) h4[i] = z;   // 5 iters
    }
    __syncthreads();
    int segL = blockIdx.x / SPLITS;
    int part = blockIdx.x % SPLITS;
    int seg  = base_seg + segL;
    const float4* p = (const float4*)(((seg & 1) ? t2 : t1)
                      + ((size_t)(seg >> 1) << LOG_N) + (size_t)part * CHUNK);
    // CHUNK/4 = 16384 float4s / block = 16 per thread = 2 outer iters of 8
    for (int k = 0; k < 2; ++k) {
        float4 v0 = p[tid + (8 * k + 0) * HTPB];
        float4 v1 = p[tid + (8 * k + 1) * HTPB];
        float4 v2 = p[tid + (8 * k + 2) * HTPB];
        float4 v3 = p[tid + (8 * k + 3) * HTPB];
        float4 v4 = p[tid + (8 * k + 4) * HTPB];
        float4 v5 = p[tid + (8 * k + 5) * HTPB];
        float4 v6 = p[tid + (8 * k + 6) * HTPB];
        float4 v7 = p[tid + (8 * k + 7) * HTPB];
        hadd(h, v0.x); hadd(h, v0.y); hadd(h, v0.z); hadd(h, v0.w);
        hadd(h, v1.x); hadd(h, v1.y); hadd(h, v1.z); hadd(h, v1.w);
        hadd(h, v2.x); hadd(h, v2.y); hadd(h, v2.z); hadd(h, v2.w);
        hadd(h, v3.x); hadd(h, v3.y); hadd(h, v3.z); hadd(h, v3.w);
        hadd(h, v4.x); hadd(h, v4.y); hadd(h, v4.z); hadd(h, v4.w);
        hadd(h, v5.x); hadd(h, v5.y); hadd(h, v5.z); hadd(h, v5.w);
        hadd(h, v6.x); hadd(h, v6.y); hadd(h, v6.z); hadd(h, v6.w);
        hadd(h, v7.x); hadd(h, v7.y); hadd(h, v7.z); hadd(h, v7.w);
    }
    __syncthreads();
    {   // pack pairs of u32 counts into u16 lanes, 16B stores
        const uint4* h4 = (const uint4*)h;
        uint4* gs4 = (uint4*)(slices + (size_t)blockIdx.x * HWORDS);
        for (int i = tid; i < HWORDS / 4; i += HTPB) {           // 3 iters
            uint4 a = h4[2 * i], b = h4[2 * i + 1];
            uint4 o;
            o.x = a.x | (a.y << 16);
            o.y = a.z | (a.w << 16);
            o.z = b.x | (b.y << 16);
            o.w = b.z | (b.w << 16);
            gs4[i] = o;
        }
    }
}

// One block per batch: merge the 2*SPLITS packed slices into an LDS diff
// array, then loss = sqrt( sum_k (CA(k)-CB(k))^2 * (val(k+1)-val(k)) / n^2 )
// via register-held per-thread diffs + block scan for the CDF prefix.
__global__ __launch_bounds__(GTPB) void integ_kernel(
        const uint32_t* slices, double* losses, int base_batch) {
    __shared__ short sdiff[NBINS];
    __shared__ int sa[GTPB], sb[GTPB];
    __shared__ double red[GTPB];
    int bl  = blockIdx.x;
    int tid = threadIdx.x;
    const uint32_t* SA = slices + (size_t)(2 * bl) * SPLITS * HWORDS;
    const uint32_t* SB = SA + (size_t)SPLITS * HWORDS;

    // merge slices: thread owns packed words w, w+GTPB, ... (exclusive -> no races)
    for (int w = tid; w < HWORDS; w += GTPB) {
        int d0 = 0, d1 = 0;
#pragma unroll
        for (int s = 0; s < SPLITS; ++s) {
            uint32_t a = SA[s * HWORDS + w];
            uint32_t b = SB[s * HWORDS + w];
            d0 += (int)(a & 0xFFFFu) - (int)(b & 0xFFFFu);
            d1 += (int)(a >> 16)     - (int)(b >> 16);
        }
        sdiff[2 * w]     = (short)d0;
        sdiff[2 * w + 1] = (short)d1;
    }
    __syncthreads();

    int k0 = tid * BPT;
    int diffs[BPT];
    int s = 0;
#pragma unroll
    for (int k = 0; k < BPT; ++k) {
        int d = sdiff[k0 + k];
        diffs[k] = d;
        s += d;
    }
    sa[tid] = s;
    __syncthreads();
    int* cur = sa; int* nxt = sb;
    for (int off = 1; off < GTPB; off <<= 1) {
        int v = cur[tid] + ((tid >= off) ? cur[tid - off] : 0);
        nxt[tid] = v;
        __syncthreads();
        int* tmp = cur; cur = nxt; nxt = tmp;
    }
    int D = (tid == 0) ? 0 : cur[tid - 1];

    double acc = 0.0;
    float vprev = key2f(dekey((uint32_t)k0));
#pragma unroll
    for (int k = 0; k < BPT; ++k) {
        D += diffs[k];
        float vnext = key2f(dekey((uint32_t)(k0 + k + 1)));  // dekey(NBINS)=0xC800, finite
        if (D) {
            double dd = (double)D;
            acc += dd * dd * (double)(vnext - vprev);
        }
        vprev = vnext;
    }

    red[tid] = acc;
    __syncthreads();
    for (int off = GTPB / 2; off > 0; off >>= 1) {
        if (tid < off) red[tid] += red[tid + off];
        __syncthreads();
    }
    if (tid == 0) {
        const double inv = 1.0 / ((double)N_PER * (double)N_PER);
        losses[base_batch + bl] = sqrt(red[0] * inv);
    }
}

__global__ void final_kernel(const double* losses, float* out) {
    int tid = threadIdx.x;   // 64 threads
    double loss = losses[tid];
    for (int off = 32; off > 0; off >>= 1)
        loss += __shfl_down(loss, off);
    if (tid == 0) out[0] = (float)(loss / (double)BATCHES);
}

extern "C" void kernel_launch(void* const* d_in, const int* in_sizes, int n_in,
                              void* d_out, int out_size, void* d_ws, size_t ws_size,
                              hipStream_t stream) {
    const float* t1 = (const float*)d_in[0];
    const float* t2 = (const float*)d_in[1];
    float* out = (float*)d_out;

    char* ws = (char*)d_ws;
    double* losses = (double*)ws;
    size_t off = 1024;
    size_t perBatch = (size_t)2 * SPLITS * HWORDS * 4;   // 320 KB of slices

    if (ws_size < off + perBatch) return;                // clean failure > GPU fault

    int CB = (int)((ws_size - off) / perBatch);
    if (CB > BATCHES) CB = BATCHES;
    uint32_t* slices = (uint32_t*)(ws + off);

    for (int base = 0; base < BATCHES; base += CB) {
        int nb = BATCHES - base < CB ? BATCHES - base : CB;
        hipLaunchKernelGGL(hist_kernel, dim3(2 * nb * SPLITS), dim3(HTPB), 0, stream,
                           t1, t2, 2 * base, slices);
        hipLaunchKernelGGL(integ_kernel, dim3(nb), dim3(GTPB), 0, stream,
                           slices, losses, base);
    }
    hipLaunchKernelGGL(final_kernel, dim3(1), dim3(BATCHES), 0, stream, losses, out);
}